// Round 11
// baseline (357.127 us; speedup 1.0000x reference)
//
#include <hip/hip_runtime.h>
#include <hip/hip_bf16.h>
#include <hip/hip_fp8.h>
#include <stdint.h>

#define NN 16384
#define DD 512
#define MARGINV 2.0f
#define EPSV 1e-6f

#define BJ 64                   // 64-j tiles: barriers halved vs r8 (drain was ~100k cyc/SIMD)
#define JGROUPS 8               // grid = 64 bi x 8 bj = 512 = 2 blocks/CU (reg- and LDS-consistent)
#define JRANGE (NN / JGROUPS)   // 2048
#define NTILES (JRANGE / BJ)    // 32
#define ROWQ 512                // fp8 row bytes
#define TILEB (BJ * ROWQ)       // 32768 B per tile buffer; 2 buffers = 64 KB (m132 precedent)

#define KEYMASK  0xFFFFC000     // keep sign+exp+9 mantissa bits; low 14 = j (j<16384)
#define KEYINITF __builtin_bit_cast(float, 0x7F000000)   // big positive finite float
#define BIASV 640.0f            // > max sq_i: keys strictly positive, self provably rank 0

typedef __attribute__((ext_vector_type(4))) float f32x4;
typedef __attribute__((ext_vector_type(4))) int   i32x4;
typedef __attribute__((ext_vector_type(8))) int   i32x8;

#define UNIT_SCALE 0x7F   // E8M0 biased exponent 127 -> x1.0

// sorted-3 insert via med3 (keys are positive finite floats; float order == int order)
__device__ inline void kins3f(float u, float& m0, float& m1, float& m2) {
  m2 = __builtin_amdgcn_fmed3f(m1, m2, u);
  m1 = __builtin_amdgcn_fmed3f(m0, m1, u);
  m0 = fminf(m0, u);
}

// ---------------- Kernel 1: row sq-norms (fp32, +BIASV) + fp8 e4m3 quantize ----------------
extern "C" __global__ __launch_bounds__(256)
void prep_kernel(const float* __restrict__ x, unsigned char* __restrict__ xq,
                 float* __restrict__ sqb, float* __restrict__ out) {
  if (blockIdx.x == 0 && threadIdx.x == 0) out[0] = 0.0f;   // replaces memset dispatch
  int row  = blockIdx.x * 4 + (threadIdx.x >> 6);
  int lane = threadIdx.x & 63;
  const float* xr = x + (size_t)row * DD + lane * 8;
  f32x4 a = *(const f32x4*)xr;
  f32x4 b = *(const f32x4*)(xr + 4);
  float s = a[0]*a[0]+a[1]*a[1]+a[2]*a[2]+a[3]*a[3]
          + b[0]*b[0]+b[1]*b[1]+b[2]*b[2]+b[3]*b[3];
  #pragma unroll
  for (int off = 1; off < 64; off <<= 1) s += __shfl_xor(s, off, 64);
  unsigned long long pkv = 0;
  #pragma unroll
  for (int t = 0; t < 4; ++t) {
    __hip_fp8_e4m3 qa(a[t]), qb(b[t]);
    pkv |= ((unsigned long long)qa.__x) << (8 * t);
    pkv |= ((unsigned long long)qb.__x) << (8 * (t + 4));
  }
  *(unsigned long long*)(xq + (size_t)row * ROWQ + lane * 8) = pkv;
  if (lane == 0) sqb[row] = s + BIASV;   // keys = sqb[j]-2dot > 0; self rank 0
}

// ---------------- Kernel 2: fused MX-fp8 GEMM (X·X^T) + per-row packed top-3 -------------
// r8 structure (best measured: LDS-staged, full 3-bit swizzle, 4 A-sets) with:
//  - BJ=64: 32 barriers instead of 64 (r8's unexplained ~100k cyc/SIMD = barrier drain)
//  - parity-split accumulators: MFMA dep-chain 4 -> 2 per (set,parity)
// mfma_scale 16x16x128 fp8 unit-scales == plain fp8 dot at 2x rate.
extern "C" __global__ __launch_bounds__(256, 2)
void knn_kernel(const unsigned char* __restrict__ xq, const float* __restrict__ sqb,
                int* __restrict__ pk) {
  __shared__ __align__(16) char lds[2 * TILEB];  // 65,536 B
  const int tid  = threadIdx.x;
  const int wave = tid >> 6;
  const int lane = tid & 63;
  const int quad = lane >> 4;
  const int r16  = lane & 15;
  const int bi   = blockIdx.x >> 3;             // 0..63
  const int bj   = blockIdx.x & 7;              // 0..7
  const int ibase = bi * 256 + wave * 64;       // 64 i-rows per wave
  const int jbase = bj * JRANGE;

  // A fragments: 4 sets x 4 k-chunks x 32 B (v8i32). A[m=r16][k=chunk*128+quad*32+t]
  i32x8 afr[4][4];
  #pragma unroll
  for (int s = 0; s < 4; ++s) {
    const unsigned char* ar = xq + (size_t)(ibase + s * 16 + r16) * ROWQ + quad * 32;
    #pragma unroll
    for (int c = 0; c < 4; ++c)
      afr[s][c] = *(const i32x8*)(ar + c * 128);
  }

  // packed top-3 per (set s, reg r): q = s*4 + r; i-row = ibase + s*16 + quad*4 + r
  float m0[16], m1[16], m2[16];
  #pragma unroll
  for (int q = 0; q < 16; ++q) { m0[q] = m1[q] = m2[q] = KEYINITF; }

  auto stage = [&](int jt, int buf) {
    const int jrow0 = jbase + jt * BJ;
    #pragma unroll
    for (int p = 0; p < 8; ++p) {
      const int rr = wave * 16 + p * 2;                  // wave-uniform local row pair
      const int lr = rr + (lane >> 5);                   // per-lane local row
      const int u  = (lane & 31) ^ (lr & 7);             // full 3-bit chunk swizzle
      const unsigned char* gsrc = xq + (size_t)(jrow0 + lr) * ROWQ + u * 16;
      char* ldst = lds + buf * TILEB + rr * ROWQ;        // wave-uniform base
      __builtin_amdgcn_global_load_lds((const __attribute__((address_space(1))) void*)gsrc,
                                       (__attribute__((address_space(3))) void*)ldst,
                                       16, 0, 0);
    }
  };

  const int sw = r16 & 7;
  stage(0, 0);
  for (int jt = 0; jt < NTILES; ++jt) {
    __syncthreads();
    if (jt + 1 < NTILES) stage(jt + 1, (jt + 1) & 1);
    #pragma unroll
    for (int jh = 0; jh < 4; ++jh) {
      const char* brow = lds + (jt & 1) * TILEB + (jh * 16 + r16) * ROWQ;
      f32x4 accE[4] = {{0.f,0.f,0.f,0.f},{0.f,0.f,0.f,0.f},
                       {0.f,0.f,0.f,0.f},{0.f,0.f,0.f,0.f}};
      f32x4 accO[4] = {{0.f,0.f,0.f,0.f},{0.f,0.f,0.f,0.f},
                       {0.f,0.f,0.f,0.f},{0.f,0.f,0.f,0.f}};
      #pragma unroll
      for (int c = 0; c < 4; ++c) {
        const int g0 = c * 8 + quad * 2;
        i32x4 lo = *(const i32x4*)(brow + ((g0       ^ sw) * 16));
        i32x4 hi = *(const i32x4*)(brow + (((g0 + 1) ^ sw) * 16));
        i32x8 bf = i32x8{lo[0],lo[1],lo[2],lo[3],hi[0],hi[1],hi[2],hi[3]};
        if (c & 1) {
          #pragma unroll
          for (int s = 0; s < 4; ++s)
            accO[s] = __builtin_amdgcn_mfma_scale_f32_16x16x128_f8f6f4(
                        afr[s][c], bf, accO[s], 0, 0, 0, UNIT_SCALE, 0, UNIT_SCALE);
        } else {
          #pragma unroll
          for (int s = 0; s < 4; ++s)
            accE[s] = __builtin_amdgcn_mfma_scale_f32_16x16x128_f8f6f4(
                        afr[s][c], bf, accE[s], 0, 0, 0, UNIT_SCALE, 0, UNIT_SCALE);
        }
      }
      const int j = jbase + jt * BJ + jh * 16 + r16;
      const float sqj = sqb[j];
      #pragma unroll
      for (int s = 0; s < 4; ++s) {
        #pragma unroll
        for (int r = 0; r < 4; ++r) {
          float d = accE[s][r] + accO[s][r];
          float v = fmaf(-2.0f, d, sqj);                 // > 0 by BIASV construction
          int   b = (__builtin_bit_cast(int, v) & KEYMASK) | j;   // v_and_or_b32
          kins3f(__builtin_bit_cast(float, b), m0[s*4+r], m1[s*4+r], m2[s*4+r]);
        }
      }
    }
  }

  // ------- in-register butterfly merge across r16 (masks 1,2,4,8 stay in-quad) -------
  #pragma unroll
  for (int m = 1; m <= 8; m <<= 1) {
    #pragma unroll
    for (int q = 0; q < 16; ++q) {
      float o0 = __shfl_xor(m0[q], m, 64);
      float o1 = __shfl_xor(m1[q], m, 64);
      float o2 = __shfl_xor(m2[q], m, 64);
      kins3f(o0, m0[q], m1[q], m2[q]);
      kins3f(o1, m0[q], m1[q], m2[q]);
      kins3f(o2, m0[q], m1[q], m2[q]);
    }
  }

  // lane with r16 == q writes row q's merged packed top-3 (16 writers x 4 quads)
  #pragma unroll
  for (int q = 0; q < 16; ++q) {
    if (r16 == q) {
      int s  = q >> 2, r = q & 3;
      int gi = ibase + s * 16 + quad * 4 + r;
      int ob = (gi * JGROUPS + bj) * 3;
      pk[ob + 0] = __builtin_bit_cast(int, m0[q]);
      pk[ob + 1] = __builtin_bit_cast(int, m1[q]);
      pk[ob + 2] = __builtin_bit_cast(int, m2[q]);
    }
  }
}

// ---------------- Kernel 3: merge partials (parallel), fp32 norms, hinge, mean ----------
extern "C" __global__ __launch_bounds__(256)
void finalize_kernel(const float* __restrict__ x, const float* __restrict__ pos,
                     const int* __restrict__ pk, float* __restrict__ out) {
  __shared__ float wsum[4];
  int i    = blockIdx.x * 4 + (threadIdx.x >> 6);
  int wave = threadIdx.x >> 6;
  int lane = threadIdx.x & 63;
  // parallel merge: lane<24 loads one partial (coalesced), 5-round butterfly over
  // lanes 0..31 (masks 1,2,4,8,16) -> lane 0 holds global top-3 (r10's lane-0
  // serial 24-load chain was ~5k cyc/block of pure latency)
  float m0 = KEYINITF, m1 = KEYINITF, m2 = KEYINITF;
  if (lane < 24) m0 = __builtin_bit_cast(float, pk[i * 24 + lane]);
  #pragma unroll
  for (int m = 1; m <= 16; m <<= 1) {
    float o0 = __shfl_xor(m0, m, 64);
    float o1 = __shfl_xor(m1, m, 64);
    float o2 = __shfl_xor(m2, m, 64);
    kins3f(o0, m0, m1, m2);
    kins3f(o1, m0, m1, m2);
    kins3f(o2, m0, m1, m2);
  }
  int neg = __shfl(__builtin_bit_cast(int, m2) & 0x3FFF, 0, 64);  // rank 2 == idx3[:,2]
  const float* xr = x   + (size_t)i * DD + lane * 8;
  const float* pr = pos + (size_t)i * DD + lane * 8;
  const float* nr = x   + (size_t)neg * DD + lane * 8;
  f32x4 xa = *(const f32x4*)xr, xb4 = *(const f32x4*)(xr + 4);
  f32x4 pa = *(const f32x4*)pr, pb  = *(const f32x4*)(pr + 4);
  f32x4 na = *(const f32x4*)nr, nb  = *(const f32x4*)(nr + 4);
  float sap = 0.f, san = 0.f;
  #pragma unroll
  for (int k = 0; k < 4; ++k) {
    float d0 = xa[k]  - pa[k] + EPSV; sap = fmaf(d0, d0, sap);
    float d1 = xa[k]  - na[k] + EPSV; san = fmaf(d1, d1, san);
    float d2 = xb4[k] - pb[k] + EPSV; sap = fmaf(d2, d2, sap);
    float d3 = xb4[k] - nb[k] + EPSV; san = fmaf(d3, d3, san);
  }
  #pragma unroll
  for (int off = 1; off < 64; off <<= 1) {
    sap += __shfl_xor(sap, off, 64);
    san += __shfl_xor(san, off, 64);
  }
  if (lane == 0) {
    float l = sqrtf(sap) - sqrtf(san) + MARGINV;
    wsum[wave] = l > 0.f ? l : 0.f;
  }
  __syncthreads();
  if (threadIdx.x == 0) {
    atomicAdd(out, (wsum[0] + wsum[1] + wsum[2] + wsum[3]) * (1.0f / NN));
  }
}

// ---------------- host ----------------
extern "C" void kernel_launch(void* const* d_in, const int* in_sizes, int n_in,
                              void* d_out, int out_size, void* d_ws, size_t ws_size,
                              hipStream_t stream) {
  const float* x   = (const float*)d_in[0];
  const float* pos = (const float*)d_in[1];
  char* ws = (char*)d_ws;
  unsigned char* xq  = (unsigned char*)ws;                                // 8 MB
  float* sqb = (float*)(ws + (size_t)NN * ROWQ);                          // 64 KB
  int*   pk  = (int*)  (ws + (size_t)NN * ROWQ + (size_t)NN * 4);         // 1.5 MB

  prep_kernel<<<NN / 4, 256, 0, stream>>>(x, xq, sqb, (float*)d_out);
  knn_kernel<<<(NN / 256) * JGROUPS, 256, 0, stream>>>(xq, sqb, pk);
  finalize_kernel<<<NN / 4, 256, 0, stream>>>(x, pos, pk, (float*)d_out);
}

// Round 12
// 342.606 us; speedup vs baseline: 1.0424x; 1.0424x over previous
//
#include <hip/hip_runtime.h>
#include <hip/hip_bf16.h>
#include <hip/hip_fp8.h>
#include <stdint.h>

#define NN 16384
#define DD 512
#define MARGINV 2.0f
#define EPSV 1e-6f

#define JGROUPS 8               // grid = 128 bi x 8 bj = 1024
#define JRANGE (NN / JGROUPS)   // 2048
#define NJT (JRANGE / 32)       // 64 32-j tiles
#define RT_STRIDE 16384         // 32 rows x 512 B, 32x32-fragment-ordered (linear stream)

#define KEYMASK  0xFFFFC000     // keep sign+exp+9 mantissa bits; low 14 = j (j<16384)
#define KEYINITF __builtin_bit_cast(float, 0x7F000000)   // big positive finite float
#define BIASV 640.0f            // > max sq_i: keys strictly positive, self provably rank 0

typedef __attribute__((ext_vector_type(4)))  float f32x4;
typedef __attribute__((ext_vector_type(16))) float f32x16;
typedef __attribute__((ext_vector_type(8)))  int   i32x8;

#define UNIT_SCALE 0x7F   // E8M0 biased exponent 127 -> x1.0

// sorted-3 insert via med3 (keys are positive finite floats; float order == int order)
__device__ inline void kins3f(float u, float& m0, float& m1, float& m2) {
  m2 = __builtin_amdgcn_fmed3f(m1, m2, u);
  m1 = __builtin_amdgcn_fmed3f(m0, m1, u);
  m0 = fminf(m0, u);
}

// ---------------- Kernel 1: sq-norms (+BIASV) + fp8 quantize into 32x32-fragment layout --
// Layout: rowtile RT (32 rows) x kchunk c (K=64): region RT*16384 + c*2048; inside:
// frag-lane = (row%32) + 32*((k%64)/32), byte = frag-lane*32 + (k%32).
// Serves both A and B operands of mfma_32x32x64 (A[m][k] and B[k][n] maps coincide).
extern "C" __global__ __launch_bounds__(256)
void prep_kernel(const float* __restrict__ x, unsigned char* __restrict__ xqB,
                 float* __restrict__ sqb, float* __restrict__ out) {
  if (blockIdx.x == 0 && threadIdx.x == 0) out[0] = 0.0f;   // replaces memset dispatch
  int row  = blockIdx.x * 4 + (threadIdx.x >> 6);
  int lane = threadIdx.x & 63;
  const float* xr = x + (size_t)row * DD + lane * 8;        // k = lane*8 .. +8
  f32x4 a = *(const f32x4*)xr;
  f32x4 b = *(const f32x4*)(xr + 4);
  float s = a[0]*a[0]+a[1]*a[1]+a[2]*a[2]+a[3]*a[3]
          + b[0]*b[0]+b[1]*b[1]+b[2]*b[2]+b[3]*b[3];
  #pragma unroll
  for (int off = 1; off < 64; off <<= 1) s += __shfl_xor(s, off, 64);
  unsigned long long pkv = 0;
  #pragma unroll
  for (int t = 0; t < 4; ++t) {
    __hip_fp8_e4m3 qa(a[t]), qb(b[t]);
    pkv |= ((unsigned long long)qa.__x) << (8 * t);
    pkv |= ((unsigned long long)qb.__x) << (8 * (t + 4));
  }
  // k = lane*8: c = lane>>3, khalf = (lane>>2)&1, k%32 base = (lane&3)*8
  size_t dst = (size_t)(row >> 5) * RT_STRIDE + (lane >> 3) * 2048
             + ((lane >> 2) & 1) * 1024 + (row & 31) * 32 + (lane & 3) * 8;
  *(unsigned long long*)(xqB + dst) = pkv;
  if (lane == 0) sqb[row] = s + BIASV;   // keys = sqb[j]-2dot > 0; self rank 0
}

// ---------------- Kernel 2: streaming MX-fp8 32x32x64 GEMM + per-row packed top-3 --------
// Hypothesis test vs the 16x16x128 plateau (r8-r10 all ~35-39% MfmaUtil): same FLOP
// rate per uebench, HALF the instruction count, 2x FLOP per operand fetch. No LDS,
// no barriers. Per wave: 1 A-set (32 i-rows, 64 regs), one f32x16 acc, 8-chunk K loop.
// ~159 regs -> 3 waves/SIMD. B is a linear 1 MB stream (fragment layout), f0/f1
// rolling prefetch. C layout: col=lane&31, row=(reg&3)+8*(reg>>2)+4*(lane>>5).
extern "C" __global__ __launch_bounds__(256, 3)
void knn_kernel(const unsigned char* __restrict__ xqB, const float* __restrict__ sqb,
                int* __restrict__ pk) {
  const int tid  = threadIdx.x;
  const int wave = tid >> 6;
  const int lane = tid & 63;
  const int col  = lane & 31;
  const int half = lane >> 5;
  const int bi   = blockIdx.x >> 3;             // 0..127
  const int bj   = blockIdx.x & 7;              // 0..7
  const int ibase = bi * 128 + wave * 32;       // 32 i-rows per wave
  const int jbase = bj * JRANGE;
  const size_t laneoff = (size_t)lane * 32;

  // A fragments: 8 k-chunks, straight from fragment layout (coalesced 2 KB each)
  i32x8 afr[8];
  {
    const unsigned char* ab = xqB + (size_t)(ibase >> 5) * RT_STRIDE + laneoff;
    #pragma unroll
    for (int c = 0; c < 8; ++c)
      afr[c] = *(const i32x8*)(ab + c * 2048);
  }

  // packed top-3 per acc reg q: i-row = ibase + (q&3) + 8*(q>>2) + 4*half
  float m0[16], m1[16], m2[16];
  #pragma unroll
  for (int q = 0; q < 16; ++q) { m0[q] = m1[q] = m2[q] = KEYINITF; }

  // linear B stream: chunk (jt,c) at bbase + (8*jt+c)*2048
  const unsigned char* pnext = xqB + (size_t)(jbase >> 5) * RT_STRIDE + laneoff;
  i32x8 f0 = *(const i32x8*)pnext;
  i32x8 f1 = *(const i32x8*)(pnext + 2048);
  pnext += 2 * 2048;

  for (int jt = 0; jt < NJT; ++jt) {
    f32x16 acc = {0.f,0.f,0.f,0.f,0.f,0.f,0.f,0.f,
                  0.f,0.f,0.f,0.f,0.f,0.f,0.f,0.f};
    #pragma unroll
    for (int c = 0; c < 8; ++c) {
      // last iter overreads 2 chunks (4 KB) into the sqb region: harmless, unused.
      i32x8 bf;
      if (c & 1) { bf = f1; f1 = *(const i32x8*)pnext; }
      else       { bf = f0; f0 = *(const i32x8*)pnext; }
      pnext += 2048;
      acc = __builtin_amdgcn_mfma_scale_f32_32x32x64_f8f6f4(
              afr[c], bf, acc, 0, 0, 0, UNIT_SCALE, 0, UNIT_SCALE);
    }
    const int j = jbase + jt * 32 + col;
    const float sqj = sqb[j];
    #pragma unroll
    for (int q = 0; q < 16; ++q) {
      float v = fmaf(-2.0f, acc[q], sqj);              // > 0 by BIASV construction
      int   b = (__builtin_bit_cast(int, v) & KEYMASK) | j;   // v_and_or_b32
      kins3f(__builtin_bit_cast(float, b), m0[q], m1[q], m2[q]);
    }
  }

  // ------- butterfly merge across the 32 cols (masks 1..16 preserve lane-half) -------
  #pragma unroll
  for (int m = 1; m <= 16; m <<= 1) {
    #pragma unroll
    for (int q = 0; q < 16; ++q) {
      float o0 = __shfl_xor(m0[q], m, 64);
      float o1 = __shfl_xor(m1[q], m, 64);
      float o2 = __shfl_xor(m2[q], m, 64);
      kins3f(o0, m0[q], m1[q], m2[q]);
      kins3f(o1, m0[q], m1[q], m2[q]);
      kins3f(o2, m0[q], m1[q], m2[q]);
    }
  }

  // writers: lane with col==q in each half writes its half's row for q
  #pragma unroll
  for (int q = 0; q < 16; ++q) {
    if (col == q) {
      int gi = ibase + (q & 3) + 8 * (q >> 2) + 4 * half;
      int ob = (gi * JGROUPS + bj) * 3;
      pk[ob + 0] = __builtin_bit_cast(int, m0[q]);
      pk[ob + 1] = __builtin_bit_cast(int, m1[q]);
      pk[ob + 2] = __builtin_bit_cast(int, m2[q]);
    }
  }
}

// ---------------- Kernel 3: merge partials (parallel), fp32 norms, hinge, mean ----------
extern "C" __global__ __launch_bounds__(256)
void finalize_kernel(const float* __restrict__ x, const float* __restrict__ pos,
                     const int* __restrict__ pk, float* __restrict__ out) {
  __shared__ float wsum[4];
  int i    = blockIdx.x * 4 + (threadIdx.x >> 6);
  int wave = threadIdx.x >> 6;
  int lane = threadIdx.x & 63;
  // parallel merge: lane<24 loads one partial (coalesced), 5-round butterfly
  float m0 = KEYINITF, m1 = KEYINITF, m2 = KEYINITF;
  if (lane < 24) m0 = __builtin_bit_cast(float, pk[i * 24 + lane]);
  #pragma unroll
  for (int m = 1; m <= 16; m <<= 1) {
    float o0 = __shfl_xor(m0, m, 64);
    float o1 = __shfl_xor(m1, m, 64);
    float o2 = __shfl_xor(m2, m, 64);
    kins3f(o0, m0, m1, m2);
    kins3f(o1, m0, m1, m2);
    kins3f(o2, m0, m1, m2);
  }
  int neg = __shfl(__builtin_bit_cast(int, m2) & 0x3FFF, 0, 64);  // rank 2 == idx3[:,2]
  const float* xr = x   + (size_t)i * DD + lane * 8;
  const float* pr = pos + (size_t)i * DD + lane * 8;
  const float* nr = x   + (size_t)neg * DD + lane * 8;
  f32x4 xa = *(const f32x4*)xr, xb4 = *(const f32x4*)(xr + 4);
  f32x4 pa = *(const f32x4*)pr, pb  = *(const f32x4*)(pr + 4);
  f32x4 na = *(const f32x4*)nr, nb  = *(const f32x4*)(nr + 4);
  float sap = 0.f, san = 0.f;
  #pragma unroll
  for (int k = 0; k < 4; ++k) {
    float d0 = xa[k]  - pa[k] + EPSV; sap = fmaf(d0, d0, sap);
    float d1 = xa[k]  - na[k] + EPSV; san = fmaf(d1, d1, san);
    float d2 = xb4[k] - pb[k] + EPSV; sap = fmaf(d2, d2, sap);
    float d3 = xb4[k] - nb[k] + EPSV; san = fmaf(d3, d3, san);
  }
  #pragma unroll
  for (int off = 1; off < 64; off <<= 1) {
    sap += __shfl_xor(sap, off, 64);
    san += __shfl_xor(san, off, 64);
  }
  if (lane == 0) {
    float l = sqrtf(sap) - sqrtf(san) + MARGINV;
    wsum[wave] = l > 0.f ? l : 0.f;
  }
  __syncthreads();
  if (threadIdx.x == 0) {
    atomicAdd(out, (wsum[0] + wsum[1] + wsum[2] + wsum[3]) * (1.0f / NN));
  }
}

// ---------------- host ----------------
extern "C" void kernel_launch(void* const* d_in, const int* in_sizes, int n_in,
                              void* d_out, int out_size, void* d_ws, size_t ws_size,
                              hipStream_t stream) {
  const float* x   = (const float*)d_in[0];
  const float* pos = (const float*)d_in[1];
  char* ws = (char*)d_ws;
  unsigned char* xqB = (unsigned char*)ws;                                // 8 MB (fragment layout)
  float* sqb = (float*)(ws + (size_t)NN * 512);                           // 64 KB
  int*   pk  = (int*)  (ws + (size_t)NN * 512 + (size_t)NN * 4);          // 1.5 MB

  prep_kernel<<<NN / 4, 256, 0, stream>>>(x, xqB, sqb, (float*)d_out);
  knn_kernel<<<(NN / 128) * JGROUPS, 256, 0, stream>>>(xqB, sqb, pk);
  finalize_kernel<<<NN / 4, 256, 0, stream>>>(x, pos, pk, (float*)d_out);
}